// Round 2
// baseline (847.424 us; speedup 1.0000x reference)
//
#include <hip/hip_runtime.h>
#include <cstdint>
#include <cstddef>

// GNN layer, B=4, N=256, D=E=256.
// cat = relu(A[b,i,:] + C[b,j,:] + edges[b,i,j,:]@W_E)
//   A = nodes@W_s + b_in, C = nodes@W_e  (W_in rows: 0..255=W_s, 256..511=W_e, 512..767=W_E)
// k_main v2: reg-staged bf16 LDS tiles (32 rows, double-buffered, XOR-swizzled),
// one barrier/tile, 4 blocks/CU, fused GEMM + coef + online softmax + weighted sum.

typedef float f32x4 __attribute__((ext_vector_type(4)));
typedef __bf16 bf16x4 __attribute__((ext_vector_type(4)));
typedef __bf16 bf16x8 __attribute__((ext_vector_type(8)));

// ---------------- k_pack: W_E -> bf16, B-fragment-friendly layout ----------------
// W_p[(kb8*256 + c)*8 + e] = bf16(W_in[(512 + kb8*8 + e)*256 + c]), kb8=0..31, c=0..255
__global__ __launch_bounds__(256) void k_pack(const float* __restrict__ W_in,
                                              __bf16* __restrict__ W_p) {
  int idx = blockIdx.x * 256 + threadIdx.x;   // 32 blocks -> 8192
  int kb8 = idx >> 8;
  int c = idx & 255;
  bf16x8 v;
#pragma unroll
  for (int e = 0; e < 8; ++e) v[e] = (__bf16)W_in[(size_t)(512 + kb8 * 8 + e) * 256 + c];
  *reinterpret_cast<bf16x8*>(W_p + (size_t)idx * 8) = v;
}

// ---------------- k_ac: A = nodes@W_s + b_in ; C = nodes@W_e  (f32) ----------------
__global__ __launch_bounds__(256) void k_ac(const float* __restrict__ nodes,
                                            const float* __restrict__ W_in,
                                            const float* __restrict__ b_in,
                                            float* __restrict__ A, float* __restrict__ C) {
  __shared__ float nd[4][256];
  const int t = threadIdx.x;
  const int row0 = blockIdx.x * 4;
#pragma unroll
  for (int r = 0; r < 4; ++r) nd[r][t] = nodes[(size_t)(row0 + r) * 256 + t];
  __syncthreads();
  float accA[4] = {0.f, 0.f, 0.f, 0.f}, accC[4] = {0.f, 0.f, 0.f, 0.f};
#pragma unroll 4
  for (int k = 0; k < 256; ++k) {
    float ws_ = W_in[(size_t)k * 256 + t];
    float we_ = W_in[(size_t)(256 + k) * 256 + t];
#pragma unroll
    for (int r = 0; r < 4; ++r) {
      accA[r] += nd[r][k] * ws_;
      accC[r] += nd[r][k] * we_;
    }
  }
  float bi = b_in[t];
#pragma unroll
  for (int r = 0; r < 4; ++r) {
    A[(size_t)(row0 + r) * 256 + t] = accA[r] + bi;
    C[(size_t)(row0 + r) * 256 + t] = accC[r];
  }
}

// ---------------- k_main v2 ----------------
// grid = B*N blocks (one per (b,i)), 256 threads = 4 waves, 8 j-tiles of 32 rows.
// LDS tiles are bf16 [32][256] with 16B-slot XOR swizzle: slot' = slot ^ (row&7).
__global__ __launch_bounds__(256, 4) void k_main(
    const float* __restrict__ edges, const float* __restrict__ aux,
    const float* __restrict__ A, const float* __restrict__ C,
    const __bf16* __restrict__ W_p, const float* __restrict__ W_coef,
    const float* __restrict__ b_coef, float* __restrict__ out_cat,
    float* __restrict__ resid) {
  __shared__ __bf16 ET[2][32 * 256];     // 2 x 16 KB
  __shared__ float coefw[2][4][32];      // per-wave coef partials, double-buffered

  const int tid = threadIdx.x;
  const int lane = tid & 63;
  const int wv = tid >> 6;
  const int l15 = lane & 15;
  const int lg = lane >> 4;
  const int bi = blockIdx.x;             // b*N + i
  const int b = bi >> 8;

  const f32x4 vzero = {0.f, 0.f, 0.f, 0.f};

  // per-lane column params: d = wv*64 + nc*16 + l15
  float pA[4], wc[4];
#pragma unroll
  for (int nc = 0; nc < 4; ++nc) {
    int d = wv * 64 + nc * 16 + l15;
    pA[nc] = A[(size_t)bi * 256 + d];
    wc[nc] = W_coef[d];
  }
  const float bcoef = b_coef[0];

  const float* eg = edges + (size_t)bi * 65536;
  float* catb = out_cat + (size_t)bi * 65536;

  float m_run = -INFINITY, l_run = 0.f;
  float r_lane[4] = {0.f, 0.f, 0.f, 0.f};

  // staging: chunk q = it*256+tid -> row = it*4+wv (0..31), 16B f32 chunk cc = lane
  f32x4 R[8];

#define STAGE_LOAD(J0, IT) \
  R[IT] = *reinterpret_cast<const f32x4*>(eg + (size_t)((J0) + (IT)*4 + wv) * 256 + (lane << 2));

#define STAGE_WRITE(BUF, IT)                                                         \
  {                                                                                  \
    int row_ = (IT)*4 + wv;                                                          \
    int slot_ = ((lane >> 1) ^ (row_ & 7));                                          \
    __bf16* p_ = &ET[BUF][row_ * 256] + slot_ * 8 + (lane & 1) * 4;                  \
    bf16x4 v_;                                                                       \
    v_[0] = (__bf16)R[IT][0]; v_[1] = (__bf16)R[IT][1];                              \
    v_[2] = (__bf16)R[IT][2]; v_[3] = (__bf16)R[IT][3];                              \
    *reinterpret_cast<bf16x4*>(p_) = v_;                                             \
  }

  // prologue: stage tile 0 into buf 0
#pragma unroll
  for (int it = 0; it < 8; ++it) STAGE_LOAD(0, it)
#pragma unroll
  for (int it = 0; it < 8; ++it) STAGE_WRITE(0, it)
  __syncthreads();

  f32x4 acc[2][4];

#pragma unroll 1
  for (int jt = 0; jt < 8; ++jt) {
    const int buf = jt & 1;
    const int j0 = jt * 32;

    // issue first half of next tile's global loads (latency hidden under MFMA)
    if (jt < 7) {
#pragma unroll
      for (int it = 0; it < 4; ++it) STAGE_LOAD(j0 + 32, it)
    }

    // ---- MFMA: 32(j) x 64(d per wave) x 256(k) ----
#pragma unroll
    for (int mr = 0; mr < 2; ++mr)
#pragma unroll
      for (int nc = 0; nc < 4; ++nc) acc[mr][nc] = vzero;

#pragma unroll
    for (int ks = 0; ks < 8; ++ks) {
      bf16x8 af[2];
#pragma unroll
      for (int mr = 0; mr < 2; ++mr) {
        int arow = mr * 16 + l15;
        int slotp = ((ks << 2) | lg) ^ (arow & 7);
        af[mr] = *reinterpret_cast<const bf16x8*>(&ET[buf][arow * 256] + slotp * 8);
      }
#pragma unroll
      for (int nc = 0; nc < 4; ++nc) {
        int col = wv * 64 + nc * 16 + l15;
        bf16x8 bw = *reinterpret_cast<const bf16x8*>(
            W_p + (((size_t)((ks << 2) | lg) * 256 + col) << 3));
        acc[0][nc] = __builtin_amdgcn_mfma_f32_16x16x32_bf16(af[0], bw, acc[0][nc], 0, 0, 0);
        acc[1][nc] = __builtin_amdgcn_mfma_f32_16x16x32_bf16(af[1], bw, acc[1][nc], 0, 0, 0);
      }
    }

    // issue second half of next tile's loads (latency hidden under epilogue)
    if (jt < 7) {
#pragma unroll
      for (int it = 4; it < 8; ++it) STAGE_LOAD(j0 + 32, it)
    }

    // ---- epilogue: +A +C, relu, store cat, coef partials ----
#pragma unroll
    for (int mr = 0; mr < 2; ++mr) {
#pragma unroll
      for (int r = 0; r < 4; ++r) {
        int jl = mr * 16 + lg * 4 + r;
        int j = j0 + jl;
        const float* Crow = C + ((size_t)(b * 256 + j)) * 256;
        float cp = 0.f;
#pragma unroll
        for (int nc = 0; nc < 4; ++nc) {
          int d = wv * 64 + nc * 16 + l15;
          float cv = fmaxf(acc[mr][nc][r] + pA[nc] + Crow[d], 0.f);
          acc[mr][nc][r] = cv;                 // keep cat in regs for weighted sum
          catb[(size_t)j * 256 + d] = cv;
          cp += cv * wc[nc];
        }
        cp += __shfl_xor(cp, 1);
        cp += __shfl_xor(cp, 2);
        cp += __shfl_xor(cp, 4);
        cp += __shfl_xor(cp, 8);
        if (l15 == 0) coefw[buf][wv][jl] = cp;
      }
    }

    // write next tile into other LDS buffer (global loads waited here by compiler)
    if (jt < 7) {
#pragma unroll
      for (int it = 0; it < 8; ++it) STAGE_WRITE(buf ^ 1, it)
    }

    __syncthreads();

    // ---- online softmax over this tile's 32 scores (redundant per wave) ----
    int jl32 = lane & 31;
    float sc = coefw[buf][0][jl32] + coefw[buf][1][jl32] + coefw[buf][2][jl32] +
               coefw[buf][3][jl32] + aux[(size_t)bi * 256 + j0 + jl32] + bcoef;
    float mt = sc;
#pragma unroll
    for (int mm = 1; mm < 32; mm <<= 1) mt = fmaxf(mt, __shfl_xor(mt, mm));
    float mnew = fmaxf(m_run, mt);
    float scalef = __expf(m_run - mnew);       // first tile: exp(-inf)=0
    float wgt = __expf(sc - mnew);
    float st = wgt;
#pragma unroll
    for (int mm = 1; mm < 32; mm <<= 1) st += __shfl_xor(st, mm);
    l_run = l_run * scalef + st;
    m_run = mnew;

    // ---- r += wgt[j] * cat[j,d] ----
#pragma unroll
    for (int nc = 0; nc < 4; ++nc) r_lane[nc] *= scalef;
#pragma unroll
    for (int mr = 0; mr < 2; ++mr) {
#pragma unroll
      for (int r = 0; r < 4; ++r) {
        float wj = __shfl(wgt, mr * 16 + lg * 4 + r);
#pragma unroll
        for (int nc = 0; nc < 4; ++nc) r_lane[nc] += wj * acc[mr][nc][r];
      }
    }
  }

  // ---- finalize residuals: reduce partials across the 4 row-groups ----
  float inv_l = 1.0f / l_run;
#pragma unroll
  for (int nc = 0; nc < 4; ++nc) {
    float r = r_lane[nc];
    r += __shfl_xor(r, 16);
    r += __shfl_xor(r, 32);
    if (lg == 0) resid[(size_t)bi * 256 + wv * 64 + nc * 16 + l15] = r * inv_l;
  }
#undef STAGE_LOAD
#undef STAGE_WRITE
}

// ---------------- k_out: nodes_out = nodes + relu(resid@W_out + b_out) ----------------
__global__ __launch_bounds__(256) void k_out(const float* __restrict__ nodes,
                                             const float* __restrict__ resid,
                                             const float* __restrict__ W_out,
                                             const float* __restrict__ b_out,
                                             float* __restrict__ out_nodes) {
  __shared__ float rs[4][256];
  const int t = threadIdx.x;
  const int row0 = blockIdx.x * 4;
#pragma unroll
  for (int r = 0; r < 4; ++r) rs[r][t] = resid[(size_t)(row0 + r) * 256 + t];
  __syncthreads();
  float acc[4] = {0.f, 0.f, 0.f, 0.f};
#pragma unroll 4
  for (int k = 0; k < 256; ++k) {
    float wv_ = W_out[(size_t)k * 256 + t];
#pragma unroll
    for (int r = 0; r < 4; ++r) acc[r] += rs[r][k] * wv_;
  }
  float bo = b_out[t];
#pragma unroll
  for (int r = 0; r < 4; ++r) {
    out_nodes[(size_t)(row0 + r) * 256 + t] =
        nodes[(size_t)(row0 + r) * 256 + t] + fmaxf(acc[r] + bo, 0.f);
  }
}

extern "C" void kernel_launch(void* const* d_in, const int* in_sizes, int n_in,
                              void* d_out, int out_size, void* d_ws, size_t ws_size,
                              hipStream_t stream) {
  const float* nodes = (const float*)d_in[0];
  const float* edges = (const float*)d_in[1];
  const float* aux = (const float*)d_in[2];
  // d_in[3] = nums (int, ==256), unused
  const float* W_in = (const float*)d_in[4];
  const float* b_in = (const float*)d_in[5];
  const float* W_coef = (const float*)d_in[6];
  const float* b_coef = (const float*)d_in[7];
  const float* W_out = (const float*)d_in[8];
  const float* b_out = (const float*)d_in[9];

  float* out_nodes = (float*)d_out;                  // [B,N,D]
  float* out_cat = out_nodes + 4 * 256 * 256;        // [B,N,N,D]

  // workspace: A (1MB) | C (1MB) | resid (1MB) | W_p bf16 (128KB)
  float* A = (float*)d_ws;
  float* Cm = A + 4 * 256 * 256;
  float* resid = Cm + 4 * 256 * 256;
  __bf16* W_p = (__bf16*)(resid + 4 * 256 * 256);

  k_pack<<<dim3(32), dim3(256), 0, stream>>>(W_in, W_p);
  k_ac<<<dim3(256), dim3(256), 0, stream>>>(nodes, W_in, b_in, A, Cm);
  k_main<<<dim3(1024), dim3(256), 0, stream>>>(edges, aux, A, Cm, W_p, W_coef, b_coef,
                                               out_cat, resid);
  k_out<<<dim3(256), dim3(256), 0, stream>>>(nodes, resid, W_out, b_out, out_nodes);
}